// Round 8
// baseline (161.133 us; speedup 1.0000x reference)
//
#include <hip/hip_runtime.h>

// BackwardRPM: 16384 independent solves, 200 steps of
//   u <- clip(u - LR * (R^T (R (tanh(u W1 + b1) W2 + b2 - spec)))[:6])
// Algebra: Qs = -LR * W2 R^T R[:, :6] (64x6), Ss = -LR * R[:, :6]^T R (6x40),
//   es = Ss (b2 - spec) per sample. Step: t = u W1 + b1; h = tanh(t);
//   u = clip(u + h Qs + es).
// Folds: tanh(t) = 1 - 2*rcp(e^{2t}+1); W1,b1 pre-scaled by K=2*log2(e);
//   colsum(Qs) folded into c2, Qs pre-scaled by -2.
// History: R7 op_sel+split-chains 110.9us (L=8, 2 waves/SIMD). R8 L=4
//   97.8us (1 wave/SIMD; busy 822cy/step matches model, idle 352cy).
//   R9/R10 MFMA offload: precision fixed by 3-limb bf16 split but perf
//   loser (limb-split VALU == displaced FMAs + exposed latency). R11
//   manual phase-interleave: small regression -> idle is NOT phase
//   clumping; one dependent stream can't fill its own stalls.
// R12 (this round): TWO independent sample-streams per wave. L=8 lanes/
//   sample, each lane carries 2 samples' 8-unit slices (streams A,B) ->
//   16 samples/wave, 1024 waves, chip full at 1 wave/SIMD. Stream B's
//   chain fills stream A's stalls (trans shadows, g-chain latency, the
//   serial butterfly->clip->tt join) and vice versa. W1/Qs constants
//   SHARED between streams (~230 VGPR). Butterfly = one asm block, 3
//   stages x 12 interleaved chains (hazards covered by construction).
//   Per-sample arithmetic chain order identical to R7 -> same absmax.

static constexpr float LR_ = 0.01f;

typedef float v2f __attribute__((ext_vector_type(2)));

__device__ __forceinline__ void pin2(v2f& x) { asm volatile("" : "+v"(x)); }

// v_pk_fma_f32 with src0 broadcast from lo/hi half (VOP3P op_sel).
#define PK_FMA_LO(T, U, W)                                                   \
    asm("v_pk_fma_f32 %0, %1, %2, %0 op_sel:[0,0,0] op_sel_hi:[0,1,1]"       \
        : "+v"(T) : "v"(U), "v"(W))
#define PK_FMA_HI(T, U, W)                                                   \
    asm("v_pk_fma_f32 %0, %1, %2, %0 op_sel:[1,0,0] op_sel_hi:[1,1,1]"       \
        : "+v"(T) : "v"(U), "v"(W))
#define PK_MUL_LO(D, U, W)                                                   \
    asm("v_pk_mul_f32 %0, %1, %2 op_sel:[0,0] op_sel_hi:[0,1]"               \
        : "=v"(D) : "v"(U), "v"(W))

__global__ __launch_bounds__(256)
__attribute__((amdgpu_waves_per_eu(1, 1)))
void solve_k(
    const float* __restrict__ spec, const float* __restrict__ W1,
    const float* __restrict__ b1,   const float* __restrict__ W2,
    const float* __restrict__ b2,   const float* __restrict__ R,
    float* __restrict__ out, int batch)
{
    __shared__ float sQs[64 * 7];  // Qs[i][j] = sQs[i*7+j]
    __shared__ float sSs[240];     // Ss[j][k] = sSs[j*40+k] (includes -LR)

    const int t = threadIdx.x;

    // ---- per-block setup: Qs = -LR * W2 R^T R6, Ss = -LR * R6^T R ----
    if (t < 64) {
        float M[8];
        #pragma unroll
        for (int p = 0; p < 8; ++p) {
            float acc = 0.f;
            for (int k = 0; k < 40; ++k) acc = fmaf(W2[t*40+k], R[p*40+k], acc);
            M[p] = acc;
        }
        #pragma unroll
        for (int j = 0; j < 6; ++j) {
            float acc = 0.f;
            #pragma unroll
            for (int p = 0; p < 8; ++p) acc = fmaf(M[p], R[p*40+j], acc);
            sQs[t*7+j] = -LR_ * acc;
        }
    } else {
        for (int idx = t - 64; idx < 240; idx += 192) {
            int j = idx / 40, k = idx % 40;
            float acc = 0.f;
            #pragma unroll
            for (int p = 0; p < 8; ++p) acc = fmaf(R[p*40+j], R[p*40+k], acc);
            sSs[idx] = -LR_ * acc;
        }
    }
    __syncthreads();

    // ---- lane roles: 8 lanes/sample, 2 streams/lane ----
    const int l   = t & 63;
    const int w   = t >> 6;
    const int sub = l & 7;       // eighth of hidden dim
    const int ib  = sub * 8;     // this lane's 8 units
    const int grp = l >> 3;      // sample group within wave (0..7)
    const int wid = blockIdx.x * 4 + w;
    const int sA  = wid * 16 + grp;       // stream A sample
    const int sB  = wid * 16 + 8 + grp;   // stream B sample
    const bool liveA = (sA < batch), liveB = (sB < batch);
    const int slA = liveA ? sA : 0, slB = liveB ? sB : 0;

    const float K = 2.8853900817779268f;  // 2*log2(e)

    // shared constants: W1K packed over hidden pairs p=0..3 (8 units)
    v2f w1kp[6][4], b1kp[4];
    #pragma unroll
    for (int j = 0; j < 6; ++j)
        #pragma unroll
        for (int p = 0; p < 4; ++p) {
            w1kp[j][p].x = K * W1[j*64 + ib + 2*p];
            w1kp[j][p].y = K * W1[j*64 + ib + 2*p + 1];
        }
    #pragma unroll
    for (int p = 0; p < 4; ++p) {
        b1kp[p].x = K * b1[ib + 2*p];
        b1kp[p].y = K * b1[ib + 2*p + 1];
    }

    // qs2p[i][m] = -2 * Qs[ib+i][2m..2m+1];  qc[j] = sum_i Qs[ib+i][j]
    v2f qs2p[8][3];
    float qc[6];
    #pragma unroll
    for (int j = 0; j < 6; ++j) qc[j] = 0.f;
    #pragma unroll
    for (int i = 0; i < 8; ++i)
        #pragma unroll
        for (int m = 0; m < 3; ++m) {
            float a = sQs[(ib + i)*7 + 2*m];
            float b = sQs[(ib + i)*7 + 2*m + 1];
            qs2p[i][m].x = -2.f * a;
            qs2p[i][m].y = -2.f * b;
            qc[2*m]   += a;
            qc[2*m+1] += b;
        }

    // per-stream es -> c2 = es/8 + qc (packed)
    float esA[6], esB[6];
    #pragma unroll
    for (int j = 0; j < 6; ++j) { esA[j] = 0.f; esB[j] = 0.f; }
    const float* spA = spec + slA * 40;
    const float* spB = spec + slB * 40;
    for (int k = 0; k < 40; ++k) {
        float vA = b2[k] - spA[k];
        float vB = b2[k] - spB[k];
        #pragma unroll
        for (int j = 0; j < 6; ++j) {
            esA[j] = fmaf(vA, sSs[j*40+k], esA[j]);
            esB[j] = fmaf(vB, sSs[j*40+k], esB[j]);
        }
    }
    v2f c2A[3], c2B[3];
    #pragma unroll
    for (int m = 0; m < 3; ++m) {
        c2A[m].x = esA[2*m]   * 0.125f + qc[2*m];
        c2A[m].y = esA[2*m+1] * 0.125f + qc[2*m+1];
        c2B[m].x = esB[2*m]   * 0.125f + qc[2*m];
        c2B[m].y = esB[2*m+1] * 0.125f + qc[2*m+1];
    }

    v2f eighth = {0.125f, 0.125f};

    // pin loop-invariants (budget 512 VGPRs at 1 wave/EU)
    #pragma unroll
    for (int j = 0; j < 6; ++j)
        #pragma unroll
        for (int p = 0; p < 4; ++p) pin2(w1kp[j][p]);
    #pragma unroll
    for (int p = 0; p < 4; ++p) pin2(b1kp[p]);
    #pragma unroll
    for (int i = 0; i < 8; ++i)
        #pragma unroll
        for (int m = 0; m < 3; ++m) pin2(qs2p[i][m]);
    #pragma unroll
    for (int m = 0; m < 3; ++m) { pin2(c2A[m]); pin2(c2B[m]); }
    pin2(eighth);

    v2f u2A[3], u2B[3];
    #pragma unroll
    for (int m = 0; m < 3; ++m) { u2A[m] = (v2f){0.5f, 0.5f}; u2B[m] = (v2f){0.5f, 0.5f}; }

    for (int step = 0; step < 200; ++step) {
        // ---- tt = b1K + u W1K, both streams (8 independent chains) ----
        v2f ttA[4], ttB[4];
        #pragma unroll
        for (int p = 0; p < 4; ++p) { ttA[p] = b1kp[p]; ttB[p] = b1kp[p]; }
        #pragma unroll
        for (int jp = 0; jp < 3; ++jp) {
            #pragma unroll
            for (int p = 0; p < 4; ++p) { PK_FMA_LO(ttA[p], u2A[jp], w1kp[2*jp][p]); }
            #pragma unroll
            for (int p = 0; p < 4; ++p) { PK_FMA_LO(ttB[p], u2B[jp], w1kp[2*jp][p]); }
            #pragma unroll
            for (int p = 0; p < 4; ++p) { PK_FMA_HI(ttA[p], u2A[jp], w1kp[2*jp+1][p]); }
            #pragma unroll
            for (int p = 0; p < 4; ++p) { PK_FMA_HI(ttB[p], u2B[jp], w1kp[2*jp+1][p]); }
        }
        // ---- r = rcp(exp2(tt)+1), 16 independent trans pairs ----
        v2f rA[4], rB[4];
        #pragma unroll
        for (int p = 0; p < 4; ++p) {
            v2f eA, eB;
            eA.x = __builtin_amdgcn_exp2f(ttA[p].x);
            eA.y = __builtin_amdgcn_exp2f(ttA[p].y);
            eB.x = __builtin_amdgcn_exp2f(ttB[p].x);
            eB.y = __builtin_amdgcn_exp2f(ttB[p].y);
            eA += (v2f){1.f, 1.f};
            eB += (v2f){1.f, 1.f};
            rA[p].x = __builtin_amdgcn_rcpf(eA.x);
            rA[p].y = __builtin_amdgcn_rcpf(eA.y);
            rB[p].x = __builtin_amdgcn_rcpf(eB.x);
            rB[p].y = __builtin_amdgcn_rcpf(eB.y);
        }
        // ---- g per stream, 2 chains each (X: units 0..3, Y: units 4..7) ----
        v2f gXA0, gXA1, gXA2, gYA0, gYA1, gYA2;
        v2f gXB0, gXB1, gXB2, gYB0, gYB1, gYB2;
        gXA0 = __builtin_elementwise_fma(u2A[0], eighth, c2A[0]);
        gXA1 = __builtin_elementwise_fma(u2A[1], eighth, c2A[1]);
        gXA2 = __builtin_elementwise_fma(u2A[2], eighth, c2A[2]);
        gXB0 = __builtin_elementwise_fma(u2B[0], eighth, c2B[0]);
        gXB1 = __builtin_elementwise_fma(u2B[1], eighth, c2B[1]);
        gXB2 = __builtin_elementwise_fma(u2B[2], eighth, c2B[2]);
        PK_MUL_LO(gYA0, rA[2], qs2p[4][0]);
        PK_MUL_LO(gYA1, rA[2], qs2p[4][1]);
        PK_MUL_LO(gYA2, rA[2], qs2p[4][2]);
        PK_MUL_LO(gYB0, rB[2], qs2p[4][0]);
        PK_MUL_LO(gYB1, rB[2], qs2p[4][1]);
        PK_MUL_LO(gYB2, rB[2], qs2p[4][2]);
        PK_FMA_LO(gXA0, rA[0], qs2p[0][0]);
        PK_FMA_LO(gXA1, rA[0], qs2p[0][1]);
        PK_FMA_LO(gXA2, rA[0], qs2p[0][2]);
        PK_FMA_LO(gXB0, rB[0], qs2p[0][0]);
        PK_FMA_LO(gXB1, rB[0], qs2p[0][1]);
        PK_FMA_LO(gXB2, rB[0], qs2p[0][2]);
        PK_FMA_HI(gYA0, rA[2], qs2p[5][0]);
        PK_FMA_HI(gYA1, rA[2], qs2p[5][1]);
        PK_FMA_HI(gYA2, rA[2], qs2p[5][2]);
        PK_FMA_HI(gYB0, rB[2], qs2p[5][0]);
        PK_FMA_HI(gYB1, rB[2], qs2p[5][1]);
        PK_FMA_HI(gYB2, rB[2], qs2p[5][2]);
        PK_FMA_HI(gXA0, rA[0], qs2p[1][0]);
        PK_FMA_HI(gXA1, rA[0], qs2p[1][1]);
        PK_FMA_HI(gXA2, rA[0], qs2p[1][2]);
        PK_FMA_HI(gXB0, rB[0], qs2p[1][0]);
        PK_FMA_HI(gXB1, rB[0], qs2p[1][1]);
        PK_FMA_HI(gXB2, rB[0], qs2p[1][2]);
        PK_FMA_LO(gYA0, rA[3], qs2p[6][0]);
        PK_FMA_LO(gYA1, rA[3], qs2p[6][1]);
        PK_FMA_LO(gYA2, rA[3], qs2p[6][2]);
        PK_FMA_LO(gYB0, rB[3], qs2p[6][0]);
        PK_FMA_LO(gYB1, rB[3], qs2p[6][1]);
        PK_FMA_LO(gYB2, rB[3], qs2p[6][2]);
        PK_FMA_LO(gXA0, rA[1], qs2p[2][0]);
        PK_FMA_LO(gXA1, rA[1], qs2p[2][1]);
        PK_FMA_LO(gXA2, rA[1], qs2p[2][2]);
        PK_FMA_LO(gXB0, rB[1], qs2p[2][0]);
        PK_FMA_LO(gXB1, rB[1], qs2p[2][1]);
        PK_FMA_LO(gXB2, rB[1], qs2p[2][2]);
        PK_FMA_HI(gYA0, rA[3], qs2p[7][0]);
        PK_FMA_HI(gYA1, rA[3], qs2p[7][1]);
        PK_FMA_HI(gYA2, rA[3], qs2p[7][2]);
        PK_FMA_HI(gYB0, rB[3], qs2p[7][0]);
        PK_FMA_HI(gYB1, rB[3], qs2p[7][1]);
        PK_FMA_HI(gYB2, rB[3], qs2p[7][2]);
        PK_FMA_HI(gXA0, rA[1], qs2p[3][0]);
        PK_FMA_HI(gXA1, rA[1], qs2p[3][1]);
        PK_FMA_HI(gXA2, rA[1], qs2p[3][2]);
        PK_FMA_HI(gXB0, rB[1], qs2p[3][0]);
        PK_FMA_HI(gXB1, rB[1], qs2p[3][1]);
        PK_FMA_HI(gXB2, rB[1], qs2p[3][2]);
        // combine -> 12 butterfly inputs
        v2f hA0 = gXA0 + gYA0, hA1 = gXA1 + gYA1, hA2 = gXA2 + gYA2;
        v2f hB0 = gXB0 + gYB0, hB1 = gXB1 + gYB1, hB2 = gXB2 + gYB2;
        float aA0 = hA0.x, aA1 = hA0.y, aA2 = hA1.x,
              aA3 = hA1.y, aA4 = hA2.x, aA5 = hA2.y;
        float aB0 = hB0.x, aB1 = hB0.y, aB2 = hB1.x,
              aB3 = hB1.y, aB4 = hB2.x, aB5 = hB2.y;
        // allreduce over 8 lanes: xor1, xor2, mirror. 12 interleaved chains
        // -> 11 instrs between dependent stages (DPP needs 2 wait states).
        asm("s_nop 1\n\t"
            "v_add_f32_dpp %0, %0, %0 quad_perm:[1,0,3,2] row_mask:0xf bank_mask:0xf bound_ctrl:0\n\t"
            "v_add_f32_dpp %1, %1, %1 quad_perm:[1,0,3,2] row_mask:0xf bank_mask:0xf bound_ctrl:0\n\t"
            "v_add_f32_dpp %2, %2, %2 quad_perm:[1,0,3,2] row_mask:0xf bank_mask:0xf bound_ctrl:0\n\t"
            "v_add_f32_dpp %3, %3, %3 quad_perm:[1,0,3,2] row_mask:0xf bank_mask:0xf bound_ctrl:0\n\t"
            "v_add_f32_dpp %4, %4, %4 quad_perm:[1,0,3,2] row_mask:0xf bank_mask:0xf bound_ctrl:0\n\t"
            "v_add_f32_dpp %5, %5, %5 quad_perm:[1,0,3,2] row_mask:0xf bank_mask:0xf bound_ctrl:0\n\t"
            "v_add_f32_dpp %6, %6, %6 quad_perm:[1,0,3,2] row_mask:0xf bank_mask:0xf bound_ctrl:0\n\t"
            "v_add_f32_dpp %7, %7, %7 quad_perm:[1,0,3,2] row_mask:0xf bank_mask:0xf bound_ctrl:0\n\t"
            "v_add_f32_dpp %8, %8, %8 quad_perm:[1,0,3,2] row_mask:0xf bank_mask:0xf bound_ctrl:0\n\t"
            "v_add_f32_dpp %9, %9, %9 quad_perm:[1,0,3,2] row_mask:0xf bank_mask:0xf bound_ctrl:0\n\t"
            "v_add_f32_dpp %10, %10, %10 quad_perm:[1,0,3,2] row_mask:0xf bank_mask:0xf bound_ctrl:0\n\t"
            "v_add_f32_dpp %11, %11, %11 quad_perm:[1,0,3,2] row_mask:0xf bank_mask:0xf bound_ctrl:0\n\t"
            "v_add_f32_dpp %0, %0, %0 quad_perm:[2,3,0,1] row_mask:0xf bank_mask:0xf bound_ctrl:0\n\t"
            "v_add_f32_dpp %1, %1, %1 quad_perm:[2,3,0,1] row_mask:0xf bank_mask:0xf bound_ctrl:0\n\t"
            "v_add_f32_dpp %2, %2, %2 quad_perm:[2,3,0,1] row_mask:0xf bank_mask:0xf bound_ctrl:0\n\t"
            "v_add_f32_dpp %3, %3, %3 quad_perm:[2,3,0,1] row_mask:0xf bank_mask:0xf bound_ctrl:0\n\t"
            "v_add_f32_dpp %4, %4, %4 quad_perm:[2,3,0,1] row_mask:0xf bank_mask:0xf bound_ctrl:0\n\t"
            "v_add_f32_dpp %5, %5, %5 quad_perm:[2,3,0,1] row_mask:0xf bank_mask:0xf bound_ctrl:0\n\t"
            "v_add_f32_dpp %6, %6, %6 quad_perm:[2,3,0,1] row_mask:0xf bank_mask:0xf bound_ctrl:0\n\t"
            "v_add_f32_dpp %7, %7, %7 quad_perm:[2,3,0,1] row_mask:0xf bank_mask:0xf bound_ctrl:0\n\t"
            "v_add_f32_dpp %8, %8, %8 quad_perm:[2,3,0,1] row_mask:0xf bank_mask:0xf bound_ctrl:0\n\t"
            "v_add_f32_dpp %9, %9, %9 quad_perm:[2,3,0,1] row_mask:0xf bank_mask:0xf bound_ctrl:0\n\t"
            "v_add_f32_dpp %10, %10, %10 quad_perm:[2,3,0,1] row_mask:0xf bank_mask:0xf bound_ctrl:0\n\t"
            "v_add_f32_dpp %11, %11, %11 quad_perm:[2,3,0,1] row_mask:0xf bank_mask:0xf bound_ctrl:0\n\t"
            "v_add_f32_dpp %0, %0, %0 row_half_mirror row_mask:0xf bank_mask:0xf bound_ctrl:0\n\t"
            "v_add_f32_dpp %1, %1, %1 row_half_mirror row_mask:0xf bank_mask:0xf bound_ctrl:0\n\t"
            "v_add_f32_dpp %2, %2, %2 row_half_mirror row_mask:0xf bank_mask:0xf bound_ctrl:0\n\t"
            "v_add_f32_dpp %3, %3, %3 row_half_mirror row_mask:0xf bank_mask:0xf bound_ctrl:0\n\t"
            "v_add_f32_dpp %4, %4, %4 row_half_mirror row_mask:0xf bank_mask:0xf bound_ctrl:0\n\t"
            "v_add_f32_dpp %5, %5, %5 row_half_mirror row_mask:0xf bank_mask:0xf bound_ctrl:0\n\t"
            "v_add_f32_dpp %6, %6, %6 row_half_mirror row_mask:0xf bank_mask:0xf bound_ctrl:0\n\t"
            "v_add_f32_dpp %7, %7, %7 row_half_mirror row_mask:0xf bank_mask:0xf bound_ctrl:0\n\t"
            "v_add_f32_dpp %8, %8, %8 row_half_mirror row_mask:0xf bank_mask:0xf bound_ctrl:0\n\t"
            "v_add_f32_dpp %9, %9, %9 row_half_mirror row_mask:0xf bank_mask:0xf bound_ctrl:0\n\t"
            "v_add_f32_dpp %10, %10, %10 row_half_mirror row_mask:0xf bank_mask:0xf bound_ctrl:0\n\t"
            "v_add_f32_dpp %11, %11, %11 row_half_mirror row_mask:0xf bank_mask:0xf bound_ctrl:0\n\t"
            : "+v"(aA0), "+v"(aA1), "+v"(aA2), "+v"(aA3), "+v"(aA4), "+v"(aA5),
              "+v"(aB0), "+v"(aB1), "+v"(aB2), "+v"(aB3), "+v"(aB4), "+v"(aB5));
        u2A[0].x = __builtin_amdgcn_fmed3f(aA0, 0.f, 1.f);
        u2A[0].y = __builtin_amdgcn_fmed3f(aA1, 0.f, 1.f);
        u2A[1].x = __builtin_amdgcn_fmed3f(aA2, 0.f, 1.f);
        u2A[1].y = __builtin_amdgcn_fmed3f(aA3, 0.f, 1.f);
        u2A[2].x = __builtin_amdgcn_fmed3f(aA4, 0.f, 1.f);
        u2A[2].y = __builtin_amdgcn_fmed3f(aA5, 0.f, 1.f);
        u2B[0].x = __builtin_amdgcn_fmed3f(aB0, 0.f, 1.f);
        u2B[0].y = __builtin_amdgcn_fmed3f(aB1, 0.f, 1.f);
        u2B[1].x = __builtin_amdgcn_fmed3f(aB2, 0.f, 1.f);
        u2B[1].y = __builtin_amdgcn_fmed3f(aB3, 0.f, 1.f);
        u2B[2].x = __builtin_amdgcn_fmed3f(aB4, 0.f, 1.f);
        u2B[2].y = __builtin_amdgcn_fmed3f(aB5, 0.f, 1.f);
    }

    if (sub == 0) {
        if (liveA) {
            float* o = out + sA * 6;
            o[0] = u2A[0].x; o[1] = u2A[0].y;
            o[2] = u2A[1].x; o[3] = u2A[1].y;
            o[4] = u2A[2].x; o[5] = u2A[2].y;
        }
        if (liveB) {
            float* o = out + sB * 6;
            o[0] = u2B[0].x; o[1] = u2B[0].y;
            o[2] = u2B[1].x; o[3] = u2B[1].y;
            o[4] = u2B[2].x; o[5] = u2B[2].y;
        }
    }
}

extern "C" void kernel_launch(void* const* d_in, const int* in_sizes, int n_in,
                              void* d_out, int out_size, void* d_ws, size_t ws_size,
                              hipStream_t stream)
{
    const float* spec = (const float*)d_in[0];  // (B,40)
    const float* W1   = (const float*)d_in[1];  // (6,64)
    const float* b1   = (const float*)d_in[2];  // (64,)
    const float* W2   = (const float*)d_in[3];  // (64,40)
    const float* b2   = (const float*)d_in[4];  // (40,)
    const float* R    = (const float*)d_in[5];  // (8,40)
    int batch = in_sizes[0] / 40;

    // 8 lanes/sample, 2 samples/lane-slot -> batch*4 threads
    int threads = batch * 4;
    int blocks  = (threads + 255) / 256;
    hipLaunchKernelGGL(solve_k, dim3(blocks), dim3(256), 0, stream,
                       spec, W1, b1, W2, b2, R, (float*)d_out, batch);
}

// Round 9
// 144.177 us; speedup vs baseline: 1.1176x; 1.1176x over previous
//
#include <hip/hip_runtime.h>

// BackwardRPM: 16384 independent solves, 200 steps of
//   u <- clip(u - LR * (R^T (R (tanh(u W1 + b1) W2 + b2 - spec)))[:6])
// Algebra: Qs = -LR * W2 R^T R[:, :6] (64x6), Ss = -LR * R[:, :6]^T R (6x40),
//   es = Ss (b2 - spec) per sample. Step: t = u W1 + b1; h = tanh(t);
//   u = clip(u + h Qs + es).
// Folds: tanh(t) = 1 - 2*rcp(e^{2t}+1); W1,b1 pre-scaled by K=2*log2(e);
//   colsum(Qs) folded into c2, Qs pre-scaled by -2.
// History: R7 110.9us (L=8). R8 L=4 97.8us. R9/R10 MFMA offload regressed
//   (limb-split cost == displaced FMAs). R11 manual reorder regressed.
//   R12 dual-stream regressed (busy rose, idle unchanged).
// MODEL (settled in R12 post-mortem): R8 busy 822cy/wave/step == static
//   VALU-issue 566 + trans 256 EXACTLY -> VALUBusy includes trans; demand
//   fully accounted. Wall/busy ratio (issue efficiency) saturates at
//   70-78% for this VOP3P+DPP+trans mix regardless of waves/SIMD
//   (R6:78% @4w, R7:77% @2w, R8:70% @1w). Not schedulable at source level
//   (3 structural probes regressed). Only lever left: reduce demand.
// R13 (this round): R8 + two demand trims.
//   (a) pair-rcp (R5-precedented, passed at absmax floor): rab=rcp(e0*e1),
//       r0=e1*rab, r1=e0*rab. Trans 256->192cy, VALU +48cy. Regime-correct
//       now: trans fully exposed at 1 wave/SIMD.
//   (b) merge g-chains (R7's split was a latency fix; issue-bound now):
//       single accumulator per m -> -3 init muls -3 combine adds = -24cy.
//   Demand 822 -> ~780cy/step. Pre-commit: >=96us -> ROOFLINE next round.

static constexpr float LR_ = 0.01f;

typedef float v2f __attribute__((ext_vector_type(2)));

__device__ __forceinline__ void pin2(v2f& x) { asm volatile("" : "+v"(x)); }

// v_pk_fma_f32 with src0 broadcast from lo/hi half (VOP3P op_sel).
#define PK_FMA_LO(T, U, W)                                                   \
    asm("v_pk_fma_f32 %0, %1, %2, %0 op_sel:[0,0,0] op_sel_hi:[0,1,1]"       \
        : "+v"(T) : "v"(U), "v"(W))
#define PK_FMA_HI(T, U, W)                                                   \
    asm("v_pk_fma_f32 %0, %1, %2, %0 op_sel:[1,0,0] op_sel_hi:[1,1,1]"       \
        : "+v"(T) : "v"(U), "v"(W))

__global__ __launch_bounds__(256)
__attribute__((amdgpu_waves_per_eu(1, 1)))
void solve_k(
    const float* __restrict__ spec, const float* __restrict__ W1,
    const float* __restrict__ b1,   const float* __restrict__ W2,
    const float* __restrict__ b2,   const float* __restrict__ R,
    float* __restrict__ out, int batch)
{
    __shared__ float sQs[64 * 7];  // Qs[i][j] = sQs[i*7+j]
    __shared__ float sSs[240];     // Ss[j][k] = sSs[j*40+k] (includes -LR)

    const int t = threadIdx.x;

    // ---- per-block setup: Qs = -LR * W2 R^T R6, Ss = -LR * R6^T R ----
    if (t < 64) {
        float M[8];
        #pragma unroll
        for (int p = 0; p < 8; ++p) {
            float acc = 0.f;
            for (int k = 0; k < 40; ++k) acc = fmaf(W2[t*40+k], R[p*40+k], acc);
            M[p] = acc;
        }
        #pragma unroll
        for (int j = 0; j < 6; ++j) {
            float acc = 0.f;
            #pragma unroll
            for (int p = 0; p < 8; ++p) acc = fmaf(M[p], R[p*40+j], acc);
            sQs[t*7+j] = -LR_ * acc;
        }
    } else {
        for (int idx = t - 64; idx < 240; idx += 192) {
            int j = idx / 40, k = idx % 40;
            float acc = 0.f;
            #pragma unroll
            for (int p = 0; p < 8; ++p) acc = fmaf(R[p*40+j], R[p*40+k], acc);
            sSs[idx] = -LR_ * acc;
        }
    }
    __syncthreads();

    // ---- per-thread constants ----
    const int tid = blockIdx.x * 256 + t;
    const int s   = tid >> 2;    // sample (16 per wave, one per quad)
    const int sub = tid & 3;     // quarter of hidden dim
    const int ib  = sub * 16;    // 16 hidden units per lane
    const bool live = (s < batch);
    const int sl = live ? s : 0;

    const float K = 2.8853900817779268f;  // 2*log2(e)

    // W1 (6,64) row-major, pre-scaled by K, packed over hidden pairs p=0..7.
    v2f w1kp[6][8], b1kp[8];
    #pragma unroll
    for (int j = 0; j < 6; ++j)
        #pragma unroll
        for (int p = 0; p < 8; ++p) {
            w1kp[j][p].x = K * W1[j*64 + ib + 2*p];
            w1kp[j][p].y = K * W1[j*64 + ib + 2*p + 1];
        }
    #pragma unroll
    for (int p = 0; p < 8; ++p) {
        b1kp[p].x = K * b1[ib + 2*p];
        b1kp[p].y = K * b1[ib + 2*p + 1];
    }

    // qs2p[i][m] = -2 * Qs[ib+i][2m..2m+1];  qc[j] = sum_i Qs[ib+i][j]
    v2f qs2p[16][3];
    float qc[6];
    #pragma unroll
    for (int j = 0; j < 6; ++j) qc[j] = 0.f;
    #pragma unroll
    for (int i = 0; i < 16; ++i)
        #pragma unroll
        for (int m = 0; m < 3; ++m) {
            float a = sQs[(ib + i)*7 + 2*m];
            float b = sQs[(ib + i)*7 + 2*m + 1];
            qs2p[i][m].x = -2.f * a;
            qs2p[i][m].y = -2.f * b;
            qc[2*m]   += a;
            qc[2*m+1] += b;
        }

    // es[j] = sum_k Ss[j][k]*(b2[k]-spec[k]);  c2[m] = es/4 + qc (packed)
    float es[6];
    #pragma unroll
    for (int j = 0; j < 6; ++j) es[j] = 0.f;
    const float* sp = spec + sl * 40;
    for (int k = 0; k < 40; ++k) {
        float v = b2[k] - sp[k];
        #pragma unroll
        for (int j = 0; j < 6; ++j) es[j] = fmaf(v, sSs[j*40+k], es[j]);
    }
    v2f c2[3];
    #pragma unroll
    for (int m = 0; m < 3; ++m) {
        c2[m].x = es[2*m]   * 0.25f + qc[2*m];
        c2[m].y = es[2*m+1] * 0.25f + qc[2*m+1];
    }

    v2f quarter = {0.25f, 0.25f};

    // pin loop-invariants (budget 512 VGPRs at 1 wave/EU)
    #pragma unroll
    for (int j = 0; j < 6; ++j)
        #pragma unroll
        for (int p = 0; p < 8; ++p) pin2(w1kp[j][p]);
    #pragma unroll
    for (int p = 0; p < 8; ++p) pin2(b1kp[p]);
    #pragma unroll
    for (int i = 0; i < 16; ++i)
        #pragma unroll
        for (int m = 0; m < 3; ++m) pin2(qs2p[i][m]);
    #pragma unroll
    for (int m = 0; m < 3; ++m) pin2(c2[m]);
    pin2(quarter);

    // u kept packed: u2[m] = {u[2m], u[2m+1]}
    v2f u2[3];
    #pragma unroll
    for (int m = 0; m < 3; ++m) u2[m] = (v2f){0.5f, 0.5f};

    for (int step = 0; step < 200; ++step) {
        // tt[p] = b1K + sum_j u[j]*W1K[j], 8 independent chains.
        v2f tt[8];
        #pragma unroll
        for (int p = 0; p < 8; ++p) tt[p] = b1kp[p];
        #pragma unroll
        for (int jp = 0; jp < 3; ++jp) {
            #pragma unroll
            for (int p = 0; p < 8; ++p) { PK_FMA_LO(tt[p], u2[jp], w1kp[2*jp][p]); }
            #pragma unroll
            for (int p = 0; p < 8; ++p) { PK_FMA_HI(tt[p], u2[jp], w1kp[2*jp+1][p]); }
        }
        // r2[p] = rcp(exp2(tt)+1) via pair-rcp: one rcp per pair.
        // (R5-precedented: rab=rcp(e0*e1); r0=e1*rab; r1=e0*rab.)
        v2f r2[8];
        #pragma unroll
        for (int p = 0; p < 8; ++p) {
            v2f e;
            e.x = __builtin_amdgcn_exp2f(tt[p].x);
            e.y = __builtin_amdgcn_exp2f(tt[p].y);
            e += (v2f){1.f, 1.f};
            float rab = __builtin_amdgcn_rcpf(e.x * e.y);
            r2[p].x = e.y * rab;
            r2[p].y = e.x * rab;
        }
        // g = u/4 + c2 + sum_i r_i * (-2 Qs[i,:]); single chain per m
        // (issue-bound now: R7's chain-split was a latency fix, costs
        // 6 extra pk ops -- removed).
        v2f g0, g1, g2v;
        g0  = __builtin_elementwise_fma(u2[0], quarter, c2[0]);
        g1  = __builtin_elementwise_fma(u2[1], quarter, c2[1]);
        g2v = __builtin_elementwise_fma(u2[2], quarter, c2[2]);
        #pragma unroll
        for (int p = 0; p < 8; ++p) {
            PK_FMA_LO(g0,  r2[p], qs2p[2*p][0]);
            PK_FMA_LO(g1,  r2[p], qs2p[2*p][1]);
            PK_FMA_LO(g2v, r2[p], qs2p[2*p][2]);
            PK_FMA_HI(g0,  r2[p], qs2p[2*p+1][0]);
            PK_FMA_HI(g1,  r2[p], qs2p[2*p+1][1]);
            PK_FMA_HI(g2v, r2[p], qs2p[2*p+1][2]);
        }
        float a0 = g0.x, a1 = g0.y, a2 = g1.x,
              a3 = g1.y, a4 = g2v.x, a5 = g2v.y;
        // allreduce over the 4-lane quad: xor1, xor2 (fused DPP adds; 6
        // chains interleaved -> >=5 instrs between dependent stages).
        asm("s_nop 1\n\t"
            "v_add_f32_dpp %0, %0, %0 quad_perm:[1,0,3,2] row_mask:0xf bank_mask:0xf bound_ctrl:0\n\t"
            "v_add_f32_dpp %1, %1, %1 quad_perm:[1,0,3,2] row_mask:0xf bank_mask:0xf bound_ctrl:0\n\t"
            "v_add_f32_dpp %2, %2, %2 quad_perm:[1,0,3,2] row_mask:0xf bank_mask:0xf bound_ctrl:0\n\t"
            "v_add_f32_dpp %3, %3, %3 quad_perm:[1,0,3,2] row_mask:0xf bank_mask:0xf bound_ctrl:0\n\t"
            "v_add_f32_dpp %4, %4, %4 quad_perm:[1,0,3,2] row_mask:0xf bank_mask:0xf bound_ctrl:0\n\t"
            "v_add_f32_dpp %5, %5, %5 quad_perm:[1,0,3,2] row_mask:0xf bank_mask:0xf bound_ctrl:0\n\t"
            "v_add_f32_dpp %0, %0, %0 quad_perm:[2,3,0,1] row_mask:0xf bank_mask:0xf bound_ctrl:0\n\t"
            "v_add_f32_dpp %1, %1, %1 quad_perm:[2,3,0,1] row_mask:0xf bank_mask:0xf bound_ctrl:0\n\t"
            "v_add_f32_dpp %2, %2, %2 quad_perm:[2,3,0,1] row_mask:0xf bank_mask:0xf bound_ctrl:0\n\t"
            "v_add_f32_dpp %3, %3, %3 quad_perm:[2,3,0,1] row_mask:0xf bank_mask:0xf bound_ctrl:0\n\t"
            "v_add_f32_dpp %4, %4, %4 quad_perm:[2,3,0,1] row_mask:0xf bank_mask:0xf bound_ctrl:0\n\t"
            "v_add_f32_dpp %5, %5, %5 quad_perm:[2,3,0,1] row_mask:0xf bank_mask:0xf bound_ctrl:0\n\t"
            : "+v"(a0), "+v"(a1), "+v"(a2), "+v"(a3), "+v"(a4), "+v"(a5));
        u2[0].x = __builtin_amdgcn_fmed3f(a0, 0.f, 1.f);
        u2[0].y = __builtin_amdgcn_fmed3f(a1, 0.f, 1.f);
        u2[1].x = __builtin_amdgcn_fmed3f(a2, 0.f, 1.f);
        u2[1].y = __builtin_amdgcn_fmed3f(a3, 0.f, 1.f);
        u2[2].x = __builtin_amdgcn_fmed3f(a4, 0.f, 1.f);
        u2[2].y = __builtin_amdgcn_fmed3f(a5, 0.f, 1.f);
    }

    if (live && sub == 0) {
        float* o = out + s * 6;
        o[0] = u2[0].x; o[1] = u2[0].y;
        o[2] = u2[1].x; o[3] = u2[1].y;
        o[4] = u2[2].x; o[5] = u2[2].y;
    }
}

extern "C" void kernel_launch(void* const* d_in, const int* in_sizes, int n_in,
                              void* d_out, int out_size, void* d_ws, size_t ws_size,
                              hipStream_t stream)
{
    const float* spec = (const float*)d_in[0];  // (B,40)
    const float* W1   = (const float*)d_in[1];  // (6,64)
    const float* b1   = (const float*)d_in[2];  // (64,)
    const float* W2   = (const float*)d_in[3];  // (64,40)
    const float* b2   = (const float*)d_in[4];  // (40,)
    const float* R    = (const float*)d_in[5];  // (8,40)
    int batch = in_sizes[0] / 40;

    int threads = batch * 4;
    int blocks  = (threads + 255) / 256;
    hipLaunchKernelGGL(solve_k, dim3(blocks), dim3(256), 0, stream,
                       spec, W1, b1, W2, b2, R, (float*)d_out, batch);
}